// Round 1
// baseline (168.549 us; speedup 1.0000x reference)
//
#include <hip/hip_runtime.h>

// Aggregation (SAN-style): out[n, g*CW+cc, h, w] =
//   sum_{kh,kw} input[n, g*CW+cc, h+kh-PAD, w+kw-PAD] * weight[n, cc, kh*K+kw, h, w]
// Shapes: input [16,256,32,32] f32, weight [16,32,49,32,32] f32, out = input shape.
// Memory-bound: 130 MB total traffic -> ~20.6 us floor at 6.3 TB/s.

#define KS   7
#define PAD  3
#define HH   32
#define WW   32
#define CW   32   // weight channels
#define GG   8    // share groups = 256/32
#define CX   256
#define PROW 38   // padded rows (32 + 2*3)
#define PSTR 40   // padded row stride in floats (16B aligned rows, cols 0..39)

__global__ __launch_bounds__(256, 2)
void aggregation_kernel(const float* __restrict__ input,
                        const float* __restrict__ weight,
                        float* __restrict__ out) {
    // One block per (n, cc): stages the 8 input channels {g*CW+cc} as
    // zero-padded 38x40 images in LDS. 8*38*40*4 = 48640 B.
    __shared__ float lds[GG * PROW * PSTR];

    const int t  = threadIdx.x;            // 0..255
    const int cc = blockIdx.x & (CW - 1);  // 0..31
    const int n  = blockIdx.x >> 5;        // 0..15

    // ---- 1) zero LDS (borders must be 0) ----
    float4* lz = reinterpret_cast<float4*>(lds);
    #pragma unroll
    for (int i = 0; i < 12; ++i) {
        int idx = t + i * 256;
        if (idx < GG * PROW * PSTR / 4)
            lz[idx] = make_float4(0.f, 0.f, 0.f, 0.f);
    }
    __syncthreads();

    // ---- 2) stage 8 channels of 32x32 input into LDS interior ----
    // 8*1024 floats = 2048 float4 chunks, 8 per thread, coalesced reads.
    const float* inbase = input + (size_t)n * CX * HH * WW;
    #pragma unroll
    for (int j = 0; j < 8; ++j) {
        int idx = t + j * 256;         // 0..2047
        int ch  = idx >> 8;            // 0..7
        int rem = idx & 255;
        int r   = rem >> 3;            // 0..31
        int c4  = (rem & 7) << 2;      // 0,4,...,28
        float4 v = *reinterpret_cast<const float4*>(
            inbase + ((size_t)(ch * CW + cc) * HH + r) * WW + c4);
        float* dst = &lds[(ch * PROW + (r + PAD)) * PSTR + (c4 + PAD)];
        dst[0] = v.x; dst[1] = v.y; dst[2] = v.z; dst[3] = v.w;
    }
    __syncthreads();

    // ---- 3) compute: each thread owns (h, w0..w0+3) for all 8 groups ----
    const int h  = t >> 3;            // 0..31
    const int w0 = (t & 7) << 2;      // 0,4,...,28

    float acc[GG][4];
    #pragma unroll
    for (int g = 0; g < GG; ++g)
        #pragma unroll
        for (int p = 0; p < 4; ++p) acc[g][p] = 0.f;

    const float* wbase = weight
        + ((size_t)n * CW + cc) * (KS * KS) * (HH * WW)
        + h * WW + w0;

    float4 wv[KS], wn[KS];

    // prefetch weights for kh = 0 (7 coalesced float4 loads)
    #pragma unroll
    for (int kw = 0; kw < KS; ++kw)
        wv[kw] = *reinterpret_cast<const float4*>(wbase + (size_t)kw * (HH * WW));

    auto compute_row = [&](int kh, const float4 (&wrow)[KS]) {
        const int row = h + kh;  // lds row index (h-PAD+kh+PAD)
        #pragma unroll
        for (int g = 0; g < GG; ++g) {
            // region: lds[g][row][w0 .. w0+11] -> 3 aligned ds_read_b128,
            // serves all 7 kw taps for 4 output columns.
            const float4* rp = reinterpret_cast<const float4*>(
                &lds[(g * PROW + row) * PSTR + w0]);
            float4 r0 = rp[0], r1 = rp[1], r2 = rp[2];
            float rr[12] = {r0.x, r0.y, r0.z, r0.w,
                            r1.x, r1.y, r1.z, r1.w,
                            r2.x, r2.y, r2.z, r2.w};
            #pragma unroll
            for (int kw = 0; kw < KS; ++kw) {
                acc[g][0] = fmaf(rr[kw + 0], wrow[kw].x, acc[g][0]);
                acc[g][1] = fmaf(rr[kw + 1], wrow[kw].y, acc[g][1]);
                acc[g][2] = fmaf(rr[kw + 2], wrow[kw].z, acc[g][2]);
                acc[g][3] = fmaf(rr[kw + 3], wrow[kw].w, acc[g][3]);
            }
        }
    };

    // main loop with next-row weight prefetch (hide HBM latency under FMAs)
    for (int kh = 0; kh < KS - 1; ++kh) {
        #pragma unroll
        for (int kw = 0; kw < KS; ++kw)
            wn[kw] = *reinterpret_cast<const float4*>(
                wbase + (size_t)((kh + 1) * KS + kw) * (HH * WW));
        compute_row(kh, wv);
        #pragma unroll
        for (int kw = 0; kw < KS; ++kw) wv[kw] = wn[kw];
    }
    compute_row(KS - 1, wv);

    // ---- 4) write out: 8 coalesced float4 stores ----
    #pragma unroll
    for (int g = 0; g < GG; ++g) {
        float4 o = make_float4(acc[g][0], acc[g][1], acc[g][2], acc[g][3]);
        *reinterpret_cast<float4*>(
            out + (((size_t)n * CX + g * CW + cc) * HH + h) * WW + w0) = o;
    }
}

extern "C" void kernel_launch(void* const* d_in, const int* in_sizes, int n_in,
                              void* d_out, int out_size, void* d_ws, size_t ws_size,
                              hipStream_t stream) {
    const float* input  = (const float*)d_in[0];
    const float* weight = (const float*)d_in[1];
    float* out = (float*)d_out;
    // grid: one block per (n, cc) = 16*32 = 512 blocks, 256 threads each
    aggregation_kernel<<<dim3(16 * CW), dim3(256), 0, stream>>>(input, weight, out);
}